// Round 3
// baseline (9916.509 us; speedup 1.0000x reference)
//
#include <hip/hip_runtime.h>

#define NN 100000
#define NE 1600000
#define NG 64

typedef long long i64;

__device__ __forceinline__ float sigm(float x){ return 1.f/(1.f+__expf(-x)); }
__device__ __forceinline__ float tanh_(float x){ return 2.f/(1.f+__expf(-2.f*x)) - 1.f; }

// ---------------- int-width detection (kept from r2; proven int32 but safe) ----------------
__global__ __launch_bounds__(512) void k_detect(const int* __restrict__ ei,
    const int* __restrict__ batch, int* __restrict__ flags){
  int t = threadIdx.x;
  __shared__ int nz_e, nz_b;
  if (t == 0){ nz_e = 0; nz_b = 0; }
  __syncthreads();
  if (ei[2*t + 1] != 0) nz_e = 1;
  int k = NN/2 - 512 + t;
  if (batch[2*k + 1] != 0) nz_b = 1;
  __syncthreads();
  if (t == 0){ flags[0] = nz_e ? 0 : 1; flags[1] = nz_b ? 0 : 1; }
}

// ---------------- transposed GRU weights: wT[l][k][jc] = w[l][jc][k] ----------------
__global__ __launch_bounds__(256) void k_prep_wT(const float* __restrict__ wih,
    const float* __restrict__ whh, float* __restrict__ wihT, float* __restrict__ whhT){
  int idx = blockIdx.x*256 + threadIdx.x;            // 3*49152 = 147456
  if (idx >= 3*49152) return;
  int l = idx/49152, r = idx - l*49152, k = r/384, jc = r - k*384;
  wihT[idx] = wih[((size_t)l*384 + jc)*128 + k];
  whhT[idx] = whh[((size_t)l*384 + jc)*128 + k];
}

// ---------------- encoder: h = relu([x|pos]@w1+b1)@w2+b2, fp32, 8 nodes/block ----------------
__global__ __launch_bounds__(128) void k_enc_n(const float* __restrict__ x,
    const float* __restrict__ pos, const float* __restrict__ w1, const float* __restrict__ b1,
    const float* __restrict__ w2, const float* __restrict__ b2, float* __restrict__ h){
  int n0 = blockIdx.x * 8, j = threadIdx.x;
  __shared__ float xr[8][68];
  __shared__ float t1[8][128];
  for (int q = j; q < 8*67; q += 128){
    int p = q/67, kk = q - p*67;
    xr[p][kk] = (kk < 64) ? x[(size_t)(n0+p)*64 + kk] : pos[(size_t)(n0+p)*3 + (kk-64)];
  }
  __syncthreads();
  float s[8];
#pragma unroll
  for (int p=0;p<8;++p) s[p] = b1[j];
  for (int k=0;k<67;++k){
    float w = w1[k*128 + j];
#pragma unroll
    for (int p=0;p<8;++p) s[p] = fmaf(xr[p][k], w, s[p]);
  }
#pragma unroll
  for (int p=0;p<8;++p) t1[p][j] = fmaxf(s[p], 0.f);
  __syncthreads();
#pragma unroll
  for (int p=0;p<8;++p) s[p] = b2[j];
  for (int k=0;k<128;++k){
    float w = w2[k*128 + j];
#pragma unroll
    for (int p=0;p<8;++p) s[p] = fmaf(t1[p][k], w, s[p]);
  }
#pragma unroll
  for (int p=0;p<8;++p) h[(size_t)(n0+p)*128 + j] = s[p];
}

// ---------------- m = h @ cw, fp32, 8 nodes/block ----------------
__global__ __launch_bounds__(128) void k_m_n(const float* __restrict__ h,
    const float* __restrict__ cw, float* __restrict__ m){
  int n0 = blockIdx.x * 8, j = threadIdx.x;
  __shared__ float hrm[8][128];
  for (int q = j; q < 1024; q += 128){
    int p = q >> 7, k = q & 127;
    hrm[p][k] = h[(size_t)(n0+p)*128 + k];
  }
  __syncthreads();
  float s[8];
#pragma unroll
  for (int p=0;p<8;++p) s[p] = 0.f;
  for (int k=0;k<128;++k){
    float w = cw[k*128 + j];
#pragma unroll
    for (int p=0;p<8;++p) s[p] = fmaf(hrm[p][k], w, s[p]);
  }
#pragma unroll
  for (int p=0;p<8;++p) m[(size_t)(n0+p)*128 + j] = s[p];
}

// ---------------- scatter: agg[dst] += m[src], literal segment_sum ----------------
__global__ __launch_bounds__(256) void k_scatter(const int* __restrict__ ei,
    const int* __restrict__ flags, const float* __restrict__ m, float* __restrict__ agg){
  long long t = (long long)blockIdx.x*256 + threadIdx.x;   // NE*128 total
  int e = (int)(t >> 7), c = (int)(t & 127);
  int src, dst;
  if (flags[0]){
    const i64* e64 = (const i64*)ei;
    src = (int)e64[e]; dst = (int)e64[NE + e];
  } else {
    src = ei[e]; dst = ei[NE + e];
  }
  atomicAdd(&agg[(size_t)dst*128 + c], m[(size_t)src*128 + c]);
}

// ---------------- GRU cell, fp32, 8 nodes/block ----------------
__global__ __launch_bounds__(128) void k_gru_n(const float* __restrict__ agg,
    float* __restrict__ h, const float* __restrict__ wihT, const float* __restrict__ whhT,
    const float* __restrict__ bih, const float* __restrict__ bhh, int apply_relu){
  int n0 = blockIdx.x * 8, jj = threadIdx.x;
  __shared__ float ag[8][128], hr[8][128];
  for (int q = jj; q < 1024; q += 128){
    int p = q >> 7, k = q & 127;
    ag[p][k] = agg[(size_t)(n0+p)*128 + k];
    hr[p][k] = h[(size_t)(n0+p)*128 + k];
  }
  __syncthreads();
  float ir[8], iz[8], in_[8], hr_[8], hz_[8], hn_[8];
#pragma unroll
  for (int p=0;p<8;++p){
    ir[p] = bih[jj]; iz[p] = bih[128+jj]; in_[p] = bih[256+jj];
    hr_[p] = bhh[jj]; hz_[p] = bhh[128+jj]; hn_[p] = bhh[256+jj];
  }
  for (int k=0;k<128;++k){
    float wi0 = wihT[k*384 + jj], wi1 = wihT[k*384 + 128 + jj], wi2 = wihT[k*384 + 256 + jj];
    float wh0 = whhT[k*384 + jj], wh1 = whhT[k*384 + 128 + jj], wh2 = whhT[k*384 + 256 + jj];
#pragma unroll
    for (int p=0;p<8;++p){
      float a = ag[p][k], hh = hr[p][k];
      ir[p] = fmaf(a, wi0, ir[p]);  iz[p] = fmaf(a, wi1, iz[p]);  in_[p] = fmaf(a, wi2, in_[p]);
      hr_[p] = fmaf(hh, wh0, hr_[p]); hz_[p] = fmaf(hh, wh1, hz_[p]); hn_[p] = fmaf(hh, wh2, hn_[p]);
    }
  }
#pragma unroll
  for (int p=0;p<8;++p){
    float r = sigm(ir[p] + hr_[p]);
    float z = sigm(iz[p] + hz_[p]);
    float nn = tanh_(in_[p] + r*hn_[p]);
    float hnew = (1.f - z)*nn + z*hr[p][jj];
    if (apply_relu) hnew = fmaxf(hnew, 0.f);
    h[(size_t)(n0+p)*128 + jj] = hnew;
  }
}

// ---------------- head: relu(h@lin1+b)@lin2+b, fp32, 8 nodes/block ----------------
__global__ __launch_bounds__(64) void k_head_n(const float* __restrict__ h,
    const float* __restrict__ l1, const float* __restrict__ b1,
    const float* __restrict__ l2, const float* __restrict__ b2, float* __restrict__ nodeout){
  int n0 = blockIdx.x * 8, j = threadIdx.x;
  __shared__ float hrow[8][128], t[8][64];
  for (int q = j; q < 1024; q += 64){
    int p = q >> 7, k = q & 127;
    hrow[p][k] = h[(size_t)(n0+p)*128 + k];
  }
  __syncthreads();
  float s[8];
#pragma unroll
  for (int p=0;p<8;++p) s[p] = b1[j];
  for (int k=0;k<128;++k){
    float w = l1[k*64 + j];
#pragma unroll
    for (int p=0;p<8;++p) s[p] = fmaf(hrow[p][k], w, s[p]);
  }
#pragma unroll
  for (int p=0;p<8;++p) t[p][j] = fmaxf(s[p], 0.f);
  __syncthreads();
  int c = j & 15;
#pragma unroll
  for (int pp=0;pp<2;++pp){
    int p = (j >> 4) + pp*4;
    float o = b2[c];
    for (int k=0;k<64;++k) o = fmaf(t[p][k], l2[k*16 + c], o);
    nodeout[(size_t)(n0+p)*16 + c] = o;
  }
}

// ---------------- readout: out[batch[n]] += nodeout[n] ----------------
__global__ __launch_bounds__(256) void k_read(const float* __restrict__ nodeout,
    const int* __restrict__ batch, const int* __restrict__ flags, float* __restrict__ out){
  int n = blockIdx.x*16 + (threadIdx.x >> 4);
  int c = threadIdx.x & 15;
  if (n >= NN) return;
  int b = flags[1] ? (int)((const i64*)batch)[n] : batch[n];
  if ((unsigned)b < (unsigned)NG)
    atomicAdd(&out[b*16 + c], nodeout[(size_t)n*16 + c]);
}

// ---------------- launch ----------------
extern "C" void kernel_launch(void* const* d_in, const int* in_sizes, int n_in,
                              void* d_out, int out_size, void* d_ws, size_t ws_size,
                              hipStream_t stream){
  const float* x        = (const float*)d_in[0];
  const float* pos      = (const float*)d_in[1];
  const int*   edge     = (const int*)d_in[2];
  const int*   batch    = (const int*)d_in[3];
  const float* node_w1  = (const float*)d_in[4];
  const float* node_b1  = (const float*)d_in[5];
  const float* node_w2  = (const float*)d_in[6];
  const float* node_b2  = (const float*)d_in[7];
  const float* conv_w   = (const float*)d_in[8];
  const float* gru_wih  = (const float*)d_in[9];
  const float* gru_whh  = (const float*)d_in[10];
  const float* gru_bih  = (const float*)d_in[11];
  const float* gru_bhh  = (const float*)d_in[12];
  const float* lin1_w   = (const float*)d_in[13];
  const float* lin1_b   = (const float*)d_in[14];
  const float* lin2_w   = (const float*)d_in[15];
  const float* lin2_b   = (const float*)d_in[16];
  float* out = (float*)d_out;

  char* p = (char*)d_ws;
  int*   flags = (int*)p;   p += 256;
  float* h     = (float*)p; p += (size_t)NN*128*4;
  float* m     = (float*)p; p += (size_t)NN*128*4;
  float* agg   = (float*)p; p += (size_t)NN*128*4;
  float* nodeout = (float*)p; p += (size_t)NN*16*4;
  float* wihT  = (float*)p; p += (size_t)3*49152*4;
  float* whhT  = (float*)p; p += (size_t)3*49152*4;

  k_detect<<<1, 512, 0, stream>>>(edge, batch, flags);
  k_prep_wT<<<(147456 + 255)/256, 256, 0, stream>>>(gru_wih, gru_whh, wihT, whhT);
  k_enc_n<<<NN/8, 128, 0, stream>>>(x, pos, node_w1, node_b1, node_w2, node_b2, h);

  for (int l = 0; l < 3; ++l){
    for (int i = 0; i < 3; ++i){
      int li = l*3 + i;
      k_m_n<<<NN/8, 128, 0, stream>>>(h, conv_w + (size_t)li*16384, m);
      hipMemsetAsync(agg, 0, (size_t)NN*128*4, stream);
      k_scatter<<<800000, 256, 0, stream>>>(edge, flags, m, agg);
      k_gru_n<<<NN/8, 128, 0, stream>>>(agg, h, wihT + (size_t)l*49152,
          whhT + (size_t)l*49152, gru_bih + l*384, gru_bhh + l*384, (i==2) ? 1 : 0);
    }
  }
  k_head_n<<<NN/8, 64, 0, stream>>>(h, lin1_w, lin1_b, lin2_w, lin2_b, nodeout);
  hipMemsetAsync(out, 0, (size_t)NG*16*4, stream);
  k_read<<<(NN + 15)/16, 256, 0, stream>>>(nodeout, batch, flags, out);
}

// Round 4
// 4290.045 us; speedup vs baseline: 2.3115x; 2.3115x over previous
//
#include <hip/hip_runtime.h>

#define NN 100000
#define NE 1600000
#define NG 64
#define MAXDEG 64

typedef long long i64;

__device__ __forceinline__ float sigm(float x){ return 1.f/(1.f+__expf(-x)); }
__device__ __forceinline__ float tanh_(float x){ return 2.f/(1.f+__expf(-2.f*x)) - 1.f; }

// ---------------- int-width detection (proven int32 on this harness; kept for safety) ----------------
__global__ __launch_bounds__(512) void k_detect(const int* __restrict__ ei,
    const int* __restrict__ batch, int* __restrict__ flags){
  int t = threadIdx.x;
  __shared__ int nz_e, nz_b;
  if (t == 0){ nz_e = 0; nz_b = 0; }
  __syncthreads();
  if (ei[2*t + 1] != 0) nz_e = 1;
  int k = NN/2 - 512 + t;
  if (batch[2*k + 1] != 0) nz_b = 1;
  __syncthreads();
  if (t == 0){ flags[0] = nz_e ? 0 : 1; flags[1] = nz_b ? 0 : 1; }
}

// ---------------- transposed GRU weights: wT[l][k][jc] = w[l][jc][k] ----------------
__global__ __launch_bounds__(256) void k_prep_wT(const float* __restrict__ wih,
    const float* __restrict__ whh, float* __restrict__ wihT, float* __restrict__ whhT){
  int idx = blockIdx.x*256 + threadIdx.x;            // 3*49152 = 147456
  if (idx >= 3*49152) return;
  int l = idx/49152, r = idx - l*49152, k = r/384, jc = r - k*384;
  wihT[idx] = wih[((size_t)l*384 + jc)*128 + k];
  whhT[idx] = whh[((size_t)l*384 + jc)*128 + k];
}

// ---------------- Weff fold: WeffT[li][k][jc] = sum_m cw[li][k][m] * wih[l][jc][m] ----------------
// block = one (li,k); 384 threads over jc; uses wihT (coalesced).
__global__ __launch_bounds__(384) void k_weff(const float* __restrict__ convw,
    const float* __restrict__ wihT, float* __restrict__ WeffT){
  int bid = blockIdx.x;               // 9*128
  int li = bid >> 7, k = bid & 127;
  int l = li / 3;
  int j = threadIdx.x;                // 0..383
  __shared__ float cwrow[128];
  if (j < 128) cwrow[j] = convw[((size_t)li*128 + k)*128 + j];
  __syncthreads();
  const float* wT = wihT + (size_t)l*49152;
  float acc = 0.f;
#pragma unroll 8
  for (int m = 0; m < 128; ++m)
    acc = fmaf(cwrow[m], wT[(size_t)m*384 + j], acc);
  WeffT[(size_t)li*49152 + (size_t)k*384 + j] = acc;
}

// ---------------- padded adjacency by dst ----------------
__global__ __launch_bounds__(256) void k_fill_edges(const int* __restrict__ ei,
    const int* __restrict__ flags, int* __restrict__ deg, int* __restrict__ col){
  int e = blockIdx.x*256 + threadIdx.x;
  if (e >= NE) return;
  int s, d;
  if (flags[0]){
    const i64* e64 = (const i64*)ei;
    s = (int)e64[e]; d = (int)e64[NE + e];
  } else {
    s = ei[e]; d = ei[NE + e];
  }
  int slot = atomicAdd(&deg[d], 1);
  if (slot < MAXDEG) col[(size_t)d*MAXDEG + slot] = s;
}

// ---------------- encoder: h = relu([x|pos]@w1+b1)@w2+b2, fp32, 8 nodes/block ----------------
__global__ __launch_bounds__(128) void k_enc_n(const float* __restrict__ x,
    const float* __restrict__ pos, const float* __restrict__ w1, const float* __restrict__ b1,
    const float* __restrict__ w2, const float* __restrict__ b2, float* __restrict__ h){
  int n0 = blockIdx.x * 8, j = threadIdx.x;
  __shared__ float xr[8][68];
  __shared__ float t1[8][128];
  for (int q = j; q < 8*67; q += 128){
    int p = q/67, kk = q - p*67;
    xr[p][kk] = (kk < 64) ? x[(size_t)(n0+p)*64 + kk] : pos[(size_t)(n0+p)*3 + (kk-64)];
  }
  __syncthreads();
  float s[8];
#pragma unroll
  for (int p=0;p<8;++p) s[p] = b1[j];
  for (int k=0;k<67;++k){
    float w = w1[k*128 + j];
#pragma unroll
    for (int p=0;p<8;++p) s[p] = fmaf(xr[p][k], w, s[p]);
  }
#pragma unroll
  for (int p=0;p<8;++p) t1[p][j] = fmaxf(s[p], 0.f);
  __syncthreads();
#pragma unroll
  for (int p=0;p<8;++p) s[p] = b2[j];
  for (int k=0;k<128;++k){
    float w = w2[k*128 + j];
#pragma unroll
    for (int p=0;p<8;++p) s[p] = fmaf(t1[p][k], w, s[p]);
  }
#pragma unroll
  for (int p=0;p<8;++p) h[(size_t)(n0+p)*128 + j] = s[p];
}

// ---------------- SpMM gather: ah[n] = sum_{e:dst=n} h[src], fp32, wave/node ----------------
__global__ __launch_bounds__(256) void k_spmm(const int* __restrict__ deg,
    const int* __restrict__ col, const float* __restrict__ h, float* __restrict__ ah){
  int node = (blockIdx.x<<2) + (threadIdx.x>>6);
  int lane = threadIdx.x & 63;
  int d = deg[node]; d = min(d, MAXDEG);
  int mysrc = col[(size_t)node*MAXDEG + lane];
  float ax = 0.f, ay = 0.f;
  for (int s = 0; s < d; ++s){
    int src = __shfl(mysrc, s, 64);
    float2 v = *(const float2*)(h + (size_t)src*128 + (lane<<1));
    ax += v.x; ay += v.y;
  }
  float2 o; o.x = ax; o.y = ay;
  *(float2*)(ah + (size_t)node*128 + (lane<<1)) = o;
}

// ---------------- fused GRU: gi = ah@WeffT + bih ; gh = h@whhT + bhh ; gates ----------------
__global__ __launch_bounds__(128) void k_gru(const float* __restrict__ ah,
    float* __restrict__ h, const float* __restrict__ WeffT, const float* __restrict__ whhT,
    const float* __restrict__ bih, const float* __restrict__ bhh, int apply_relu){
  int n0 = blockIdx.x * 8, jj = threadIdx.x;
  __shared__ float ag[8][128], hr[8][128];
  for (int q = jj; q < 1024; q += 128){
    int p = q >> 7, k = q & 127;
    ag[p][k] = ah[(size_t)(n0+p)*128 + k];
    hr[p][k] = h[(size_t)(n0+p)*128 + k];
  }
  __syncthreads();
  float ir[8], iz[8], in_[8], hr_[8], hz_[8], hn_[8];
#pragma unroll
  for (int p=0;p<8;++p){
    ir[p] = bih[jj]; iz[p] = bih[128+jj]; in_[p] = bih[256+jj];
    hr_[p] = bhh[jj]; hz_[p] = bhh[128+jj]; hn_[p] = bhh[256+jj];
  }
  for (int k=0;k<128;++k){
    float wi0 = WeffT[k*384 + jj], wi1 = WeffT[k*384 + 128 + jj], wi2 = WeffT[k*384 + 256 + jj];
    float wh0 = whhT[k*384 + jj],  wh1 = whhT[k*384 + 128 + jj],  wh2 = whhT[k*384 + 256 + jj];
#pragma unroll
    for (int p=0;p<8;++p){
      float a = ag[p][k], hh = hr[p][k];
      ir[p] = fmaf(a, wi0, ir[p]);   iz[p] = fmaf(a, wi1, iz[p]);   in_[p] = fmaf(a, wi2, in_[p]);
      hr_[p] = fmaf(hh, wh0, hr_[p]); hz_[p] = fmaf(hh, wh1, hz_[p]); hn_[p] = fmaf(hh, wh2, hn_[p]);
    }
  }
#pragma unroll
  for (int p=0;p<8;++p){
    float r = sigm(ir[p] + hr_[p]);
    float z = sigm(iz[p] + hz_[p]);
    float nn = tanh_(in_[p] + r*hn_[p]);
    float hnew = (1.f - z)*nn + z*hr[p][jj];
    if (apply_relu) hnew = fmaxf(hnew, 0.f);
    h[(size_t)(n0+p)*128 + jj] = hnew;
  }
}

// ---------------- head: relu(h@lin1+b)@lin2+b, fp32, 8 nodes/block ----------------
__global__ __launch_bounds__(64) void k_head_n(const float* __restrict__ h,
    const float* __restrict__ l1, const float* __restrict__ b1,
    const float* __restrict__ l2, const float* __restrict__ b2, float* __restrict__ nodeout){
  int n0 = blockIdx.x * 8, j = threadIdx.x;
  __shared__ float hrow[8][128], t[8][64];
  for (int q = j; q < 1024; q += 64){
    int p = q >> 7, k = q & 127;
    hrow[p][k] = h[(size_t)(n0+p)*128 + k];
  }
  __syncthreads();
  float s[8];
#pragma unroll
  for (int p=0;p<8;++p) s[p] = b1[j];
  for (int k=0;k<128;++k){
    float w = l1[k*64 + j];
#pragma unroll
    for (int p=0;p<8;++p) s[p] = fmaf(hrow[p][k], w, s[p]);
  }
#pragma unroll
  for (int p=0;p<8;++p) t[p][j] = fmaxf(s[p], 0.f);
  __syncthreads();
  int c = j & 15;
#pragma unroll
  for (int pp=0;pp<2;++pp){
    int p = (j >> 4) + pp*4;
    float o = b2[c];
    for (int k=0;k<64;++k) o = fmaf(t[p][k], l2[k*16 + c], o);
    nodeout[(size_t)(n0+p)*16 + c] = o;
  }
}

// ---------------- readout: out[batch[n]] += nodeout[n] ----------------
__global__ __launch_bounds__(256) void k_read(const float* __restrict__ nodeout,
    const int* __restrict__ batch, const int* __restrict__ flags, float* __restrict__ out){
  int n = blockIdx.x*16 + (threadIdx.x >> 4);
  int c = threadIdx.x & 15;
  if (n >= NN) return;
  int b = flags[1] ? (int)((const i64*)batch)[n] : batch[n];
  if ((unsigned)b < (unsigned)NG)
    atomicAdd(&out[b*16 + c], nodeout[(size_t)n*16 + c]);
}

// ---------------- launch ----------------
extern "C" void kernel_launch(void* const* d_in, const int* in_sizes, int n_in,
                              void* d_out, int out_size, void* d_ws, size_t ws_size,
                              hipStream_t stream){
  const float* x        = (const float*)d_in[0];
  const float* pos      = (const float*)d_in[1];
  const int*   edge     = (const int*)d_in[2];
  const int*   batch    = (const int*)d_in[3];
  const float* node_w1  = (const float*)d_in[4];
  const float* node_b1  = (const float*)d_in[5];
  const float* node_w2  = (const float*)d_in[6];
  const float* node_b2  = (const float*)d_in[7];
  const float* conv_w   = (const float*)d_in[8];
  const float* gru_wih  = (const float*)d_in[9];
  const float* gru_whh  = (const float*)d_in[10];
  const float* gru_bih  = (const float*)d_in[11];
  const float* gru_bhh  = (const float*)d_in[12];
  const float* lin1_w   = (const float*)d_in[13];
  const float* lin1_b   = (const float*)d_in[14];
  const float* lin2_w   = (const float*)d_in[15];
  const float* lin2_b   = (const float*)d_in[16];
  float* out = (float*)d_out;

  char* p = (char*)d_ws;
  int*   flags = (int*)p;   p += 256;
  float* h     = (float*)p; p += (size_t)NN*128*4;
  float* ah    = (float*)p; p += (size_t)NN*128*4;
  float* nodeout = (float*)p; p += (size_t)NN*16*4;
  int*   deg   = (int*)p;   p += (size_t)NN*4;
  int*   col   = (int*)p;   p += (size_t)NN*MAXDEG*4;
  float* wihT  = (float*)p; p += (size_t)3*49152*4;
  float* whhT  = (float*)p; p += (size_t)3*49152*4;
  float* WeffT = (float*)p; p += (size_t)9*49152*4;

  k_detect<<<1, 512, 0, stream>>>(edge, batch, flags);
  hipMemsetAsync(deg, 0, (size_t)NN*4, stream);
  k_prep_wT<<<(147456 + 255)/256, 256, 0, stream>>>(gru_wih, gru_whh, wihT, whhT);
  k_weff<<<9*128, 384, 0, stream>>>(conv_w, wihT, WeffT);
  k_fill_edges<<<NE/256, 256, 0, stream>>>(edge, flags, deg, col);
  k_enc_n<<<NN/8, 128, 0, stream>>>(x, pos, node_w1, node_b1, node_w2, node_b2, h);

  for (int l = 0; l < 3; ++l){
    for (int i = 0; i < 3; ++i){
      int li = l*3 + i;
      k_spmm<<<NN/4, 256, 0, stream>>>(deg, col, h, ah);
      k_gru<<<NN/8, 128, 0, stream>>>(ah, h, WeffT + (size_t)li*49152,
          whhT + (size_t)l*49152, gru_bih + l*384, gru_bhh + l*384, (i==2) ? 1 : 0);
    }
  }
  k_head_n<<<NN/8, 64, 0, stream>>>(h, lin1_w, lin1_b, lin2_w, lin2_b, nodeout);
  hipMemsetAsync(out, 0, (size_t)NG*16*4, stream);
  k_read<<<(NN + 15)/16, 256, 0, stream>>>(nodeout, batch, flags, out);
}

// Round 5
// 3169.455 us; speedup vs baseline: 3.1288x; 1.3536x over previous
//
#include <hip/hip_runtime.h>

#define NN 100000
#define NE 1600000
#define NG 64
#define MAXDEG 64

typedef long long i64;
typedef unsigned short u16;
typedef __attribute__((ext_vector_type(8))) _Float16 f16x8;
typedef __attribute__((ext_vector_type(4))) _Float16 half4;
typedef __attribute__((ext_vector_type(4))) float f32x4;

__device__ __forceinline__ float sigm(float x){ return 1.f/(1.f+__expf(-x)); }
__device__ __forceinline__ float tanh_(float x){ return 2.f/(1.f+__expf(-2.f*x)) - 1.f; }
__device__ __forceinline__ f32x4 mfma16h(f16x8 a, f16x8 b, f32x4 c){
  return __builtin_amdgcn_mfma_f32_16x16x32_f16(a,b,c,0,0,0);
}

// ---------------- int-width detection ----------------
__global__ __launch_bounds__(512) void k_detect(const int* __restrict__ ei,
    const int* __restrict__ batch, int* __restrict__ flags){
  int t = threadIdx.x;
  __shared__ int nz_e, nz_b;
  if (t == 0){ nz_e = 0; nz_b = 0; }
  __syncthreads();
  if (ei[2*t + 1] != 0) nz_e = 1;
  int k = NN/2 - 512 + t;
  if (batch[2*k + 1] != 0) nz_b = 1;
  __syncthreads();
  if (t == 0){ flags[0] = nz_e ? 0 : 1; flags[1] = nz_b ? 0 : 1; }
}

// ---------------- transposed GRU weights: wT[l][k][jc] = w[l][jc][k] ----------------
__global__ __launch_bounds__(256) void k_prep_wT(const float* __restrict__ wih,
    const float* __restrict__ whh, float* __restrict__ wihT, float* __restrict__ whhT){
  int idx = blockIdx.x*256 + threadIdx.x;            // 3*49152 = 147456
  if (idx >= 3*49152) return;
  int l = idx/49152, r = idx - l*49152, k = r/384, jc = r - k*384;
  wihT[idx] = wih[((size_t)l*384 + jc)*128 + k];
  whhT[idx] = whh[((size_t)l*384 + jc)*128 + k];
}

// ---------------- Weff fold: WeffT[li][k][jc] = sum_m cw[li][k][m] * wih[l][jc][m] ----------------
__global__ __launch_bounds__(384) void k_weff(const float* __restrict__ convw,
    const float* __restrict__ wihT, float* __restrict__ WeffT){
  int bid = blockIdx.x;               // 9*128
  int li = bid >> 7, k = bid & 127;
  int l = li / 3;
  int j = threadIdx.x;                // 0..383
  __shared__ float cwrow[128];
  if (j < 128) cwrow[j] = convw[((size_t)li*128 + k)*128 + j];
  __syncthreads();
  const float* wT = wihT + (size_t)l*49152;
  float acc = 0.f;
#pragma unroll 8
  for (int m = 0; m < 128; ++m)
    acc = fmaf(cwrow[m], wT[(size_t)m*384 + j], acc);
  WeffT[(size_t)li*49152 + (size_t)k*384 + j] = acc;
}

// ---------------- split fp16 B planes: Bcat[li][col(512)][k(256)] ----------------
// col<256: k<128 -> WeffT[li][k][col], k>=128 -> whhT[l][k-128][col]   (r,z sums)
// col in [256,384): k<128 -> WeffT[li][k][col] else 0                   (inn)
// col in [384,512): k>=128 -> whhT[l][k-128][col-128] else 0            (hn)
__global__ __launch_bounds__(256) void k_bsplit(const float* __restrict__ WeffT,
    const float* __restrict__ whhT, u16* __restrict__ Bhi, u16* __restrict__ Blo){
  int idx = blockIdx.x*256 + threadIdx.x;   // 9*512*256 exact
  int li = idx >> 17;
  int r = idx & 131071;
  int col = r >> 8, k = r & 255;
  int l = li / 3;
  float v = 0.f;
  if (k < 128){
    if (col < 384) v = WeffT[(size_t)li*49152 + (size_t)k*384 + col];
  } else {
    int k2 = k - 128;
    if (col < 256)       v = whhT[(size_t)l*49152 + (size_t)k2*384 + col];
    else if (col >= 384) v = whhT[(size_t)l*49152 + (size_t)k2*384 + (col-128)];
  }
  _Float16 hi = (_Float16)v;
  _Float16 lo = (_Float16)(v - (float)hi);
  Bhi[idx] = *(const u16*)&hi;
  Blo[idx] = *(const u16*)&lo;
}

// ---------------- padded adjacency by dst ----------------
__global__ __launch_bounds__(256) void k_fill_edges(const int* __restrict__ ei,
    const int* __restrict__ flags, int* __restrict__ deg, int* __restrict__ col){
  int e = blockIdx.x*256 + threadIdx.x;
  if (e >= NE) return;
  int s, d;
  if (flags[0]){
    const i64* e64 = (const i64*)ei;
    s = (int)e64[e]; d = (int)e64[NE + e];
  } else {
    s = ei[e]; d = ei[NE + e];
  }
  int slot = atomicAdd(&deg[d], 1);
  if (slot < MAXDEG) col[(size_t)d*MAXDEG + slot] = s;
}

// ---------------- encoder: fp32, 8 nodes/block (unchanged, proven) ----------------
__global__ __launch_bounds__(128) void k_enc_n(const float* __restrict__ x,
    const float* __restrict__ pos, const float* __restrict__ w1, const float* __restrict__ b1,
    const float* __restrict__ w2, const float* __restrict__ b2, float* __restrict__ h){
  int n0 = blockIdx.x * 8, j = threadIdx.x;
  __shared__ float xr[8][68];
  __shared__ float t1[8][128];
  for (int q = j; q < 8*67; q += 128){
    int p = q/67, kk = q - p*67;
    xr[p][kk] = (kk < 64) ? x[(size_t)(n0+p)*64 + kk] : pos[(size_t)(n0+p)*3 + (kk-64)];
  }
  __syncthreads();
  float s[8];
#pragma unroll
  for (int p=0;p<8;++p) s[p] = b1[j];
  for (int k=0;k<67;++k){
    float w = w1[k*128 + j];
#pragma unroll
    for (int p=0;p<8;++p) s[p] = fmaf(xr[p][k], w, s[p]);
  }
#pragma unroll
  for (int p=0;p<8;++p) t1[p][j] = fmaxf(s[p], 0.f);
  __syncthreads();
#pragma unroll
  for (int p=0;p<8;++p) s[p] = b2[j];
  for (int k=0;k<128;++k){
    float w = w2[k*128 + j];
#pragma unroll
    for (int p=0;p<8;++p) s[p] = fmaf(t1[p][k], w, s[p]);
  }
#pragma unroll
  for (int p=0;p<8;++p) h[(size_t)(n0+p)*128 + j] = s[p];
}

// ---------------- SpMM gather (unchanged) ----------------
__global__ __launch_bounds__(256) void k_spmm(const int* __restrict__ deg,
    const int* __restrict__ col, const float* __restrict__ h, float* __restrict__ ah){
  int node = (blockIdx.x<<2) + (threadIdx.x>>6);
  int lane = threadIdx.x & 63;
  int d = deg[node]; d = min(d, MAXDEG);
  int mysrc = col[(size_t)node*MAXDEG + lane];
  float ax = 0.f, ay = 0.f;
  for (int s = 0; s < d; ++s){
    int src = __shfl(mysrc, s, 64);
    float2 v = *(const float2*)(h + (size_t)src*128 + (lane<<1));
    ax += v.x; ay += v.y;
  }
  float2 o; o.x = ax; o.y = ay;
  *(float2*)(ah + (size_t)node*128 + (lane<<1)) = o;
}

// ---------------- fused GRU: split-fp16 3-pass MFMA + gate epilogue ----------------
// A = [ah | h] per node (K=256), split hi/lo fp16 in LDS (XOR-swizzled chunks).
// acc groups: 0=rsum(K=256), 1=zsum(K=256), 2=inn(K<128), 3=hn(K>=128).
__global__ __launch_bounds__(256) void k_gru_mfma(const float* __restrict__ ah,
    float* __restrict__ h, const u16* __restrict__ Bhi, const u16* __restrict__ Blo,
    const float* __restrict__ bih, const float* __restrict__ bhh, int apply_relu){
  __shared__ u16 Ahi[32*256];
  __shared__ u16 Alo[32*256];
  const int tid = threadIdx.x, lane = tid & 63, w = tid >> 6;
  const int tile = blockIdx.x * 32;          // 3125*32 = 100000 exact

  // stage: ah -> cols 0..127, h -> cols 128..255, split hi/lo, swizzled
#pragma unroll
  for (int half = 0; half < 2; ++half){
    const float* src = half ? h : ah;
#pragma unroll
    for (int i = 0; i < 4; ++i){
      int f = i*256 + tid;                   // 0..1023
      int row = f >> 5, colq = f & 31;
      float4 v = *(const float4*)(src + (size_t)(tile+row)*128 + colq*4);
      int colu = half*128 + colq*4;
      int chunk = colu >> 3, e4 = colu & 7;  // e4 in {0,4}
      int cs = chunk ^ (row & 7);
      int idx = row*256 + cs*8 + e4;
      _Float16 h0=(_Float16)v.x, h1=(_Float16)v.y, h2=(_Float16)v.z, h3=(_Float16)v.w;
      _Float16 l0=(_Float16)(v.x-(float)h0), l1=(_Float16)(v.y-(float)h1),
               l2=(_Float16)(v.z-(float)h2), l3=(_Float16)(v.w-(float)h3);
      half4 hv = {h0,h1,h2,h3};
      half4 lv = {l0,l1,l2,l3};
      *(half4*)(Ahi + idx) = hv;
      *(half4*)(Alo + idx) = lv;
    }
  }
  __syncthreads();

  const f32x4 fz = {0.f,0.f,0.f,0.f};
  f32x4 acc[4][2][2];
#pragma unroll
  for (int g=0;g<4;++g)
#pragma unroll
    for (int c=0;c<2;++c)
#pragma unroll
      for (int R=0;R<2;++R) acc[g][c][R] = fz;

#pragma unroll
  for (int kk = 0; kk < 8; ++kk){
    f16x8 a_hi[2], a_lo[2];
#pragma unroll
    for (int R=0;R<2;++R){
      int arow = R*16 + (lane&15);
      int cs = (kk*4 + (lane>>4)) ^ (arow & 7);
      a_hi[R] = *(const f16x8*)(Ahi + arow*256 + cs*8);
      a_lo[R] = *(const f16x8*)(Alo + arow*256 + cs*8);
    }
#pragma unroll
    for (int g=0; g<4; ++g){
      if (g==2 && kk>=4) continue;   // inn: K[0,128) only
      if (g==3 && kk<4) continue;    // hn : K[128,256) only
#pragma unroll
      for (int c=0;c<2;++c){
        size_t boff = (size_t)(g*128 + w*32 + c*16 + (lane&15))*256 + kk*32 + ((lane>>4)<<3);
        f16x8 bh = *(const f16x8*)(Bhi + boff);
        f16x8 bl = *(const f16x8*)(Blo + boff);
#pragma unroll
        for (int R=0;R<2;++R){
          acc[g][c][R] = mfma16h(a_hi[R], bh, acc[g][c][R]);
          acc[g][c][R] = mfma16h(a_hi[R], bl, acc[g][c][R]);
          acc[g][c][R] = mfma16h(a_lo[R], bh, acc[g][c][R]);
        }
      }
    }
  }

#pragma unroll
  for (int c=0;c<2;++c){
    int jj = w*32 + c*16 + (lane&15);
    float br  = bih[jj]     + bhh[jj];
    float bz  = bih[128+jj] + bhh[128+jj];
    float bin = bih[256+jj];
    float bhn = bhh[256+jj];
#pragma unroll
    for (int R=0;R<2;++R)
#pragma unroll
      for (int v=0;v<4;++v){
        int r_ = R*16 + ((lane>>4)<<2) + v;
        float rg = sigm(acc[0][c][R][v] + br);
        float zg = sigm(acc[1][c][R][v] + bz);
        float hnv = acc[3][c][R][v] + bhn;
        float ng = tanh_(acc[2][c][R][v] + bin + rg*hnv);
        int colu = 128 + jj;
        int cs = (colu >> 3) ^ (r_ & 7);
        int lidx = r_*256 + cs*8 + (colu & 7);
        float hold = (float)(*(const _Float16*)(Ahi + lidx))
                   + (float)(*(const _Float16*)(Alo + lidx));
        float hnew = (1.f - zg)*ng + zg*hold;
        if (apply_relu) hnew = fmaxf(hnew, 0.f);
        h[(size_t)(tile + r_)*128 + jj] = hnew;
      }
  }
}

// ---------------- head: fp32, 8 nodes/block (unchanged) ----------------
__global__ __launch_bounds__(64) void k_head_n(const float* __restrict__ h,
    const float* __restrict__ l1, const float* __restrict__ b1,
    const float* __restrict__ l2, const float* __restrict__ b2, float* __restrict__ nodeout){
  int n0 = blockIdx.x * 8, j = threadIdx.x;
  __shared__ float hrow[8][128], t[8][64];
  for (int q = j; q < 1024; q += 64){
    int p = q >> 7, k = q & 127;
    hrow[p][k] = h[(size_t)(n0+p)*128 + k];
  }
  __syncthreads();
  float s[8];
#pragma unroll
  for (int p=0;p<8;++p) s[p] = b1[j];
  for (int k=0;k<128;++k){
    float w = l1[k*64 + j];
#pragma unroll
    for (int p=0;p<8;++p) s[p] = fmaf(hrow[p][k], w, s[p]);
  }
#pragma unroll
  for (int p=0;p<8;++p) t[p][j] = fmaxf(s[p], 0.f);
  __syncthreads();
  int c = j & 15;
#pragma unroll
  for (int pp=0;pp<2;++pp){
    int p = (j >> 4) + pp*4;
    float o = b2[c];
    for (int k=0;k<64;++k) o = fmaf(t[p][k], l2[k*16 + c], o);
    nodeout[(size_t)(n0+p)*16 + c] = o;
  }
}

// ---------------- readout ----------------
__global__ __launch_bounds__(256) void k_read(const float* __restrict__ nodeout,
    const int* __restrict__ batch, const int* __restrict__ flags, float* __restrict__ out){
  int n = blockIdx.x*16 + (threadIdx.x >> 4);
  int c = threadIdx.x & 15;
  if (n >= NN) return;
  int b = flags[1] ? (int)((const i64*)batch)[n] : batch[n];
  if ((unsigned)b < (unsigned)NG)
    atomicAdd(&out[b*16 + c], nodeout[(size_t)n*16 + c]);
}

// ---------------- launch ----------------
extern "C" void kernel_launch(void* const* d_in, const int* in_sizes, int n_in,
                              void* d_out, int out_size, void* d_ws, size_t ws_size,
                              hipStream_t stream){
  const float* x        = (const float*)d_in[0];
  const float* pos      = (const float*)d_in[1];
  const int*   edge     = (const int*)d_in[2];
  const int*   batch    = (const int*)d_in[3];
  const float* node_w1  = (const float*)d_in[4];
  const float* node_b1  = (const float*)d_in[5];
  const float* node_w2  = (const float*)d_in[6];
  const float* node_b2  = (const float*)d_in[7];
  const float* conv_w   = (const float*)d_in[8];
  const float* gru_wih  = (const float*)d_in[9];
  const float* gru_whh  = (const float*)d_in[10];
  const float* gru_bih  = (const float*)d_in[11];
  const float* gru_bhh  = (const float*)d_in[12];
  const float* lin1_w   = (const float*)d_in[13];
  const float* lin1_b   = (const float*)d_in[14];
  const float* lin2_w   = (const float*)d_in[15];
  const float* lin2_b   = (const float*)d_in[16];
  float* out = (float*)d_out;

  char* p = (char*)d_ws;
  int*   flags = (int*)p;   p += 256;
  float* h     = (float*)p; p += (size_t)NN*128*4;
  float* ah    = (float*)p; p += (size_t)NN*128*4;
  float* nodeout = (float*)p; p += (size_t)NN*16*4;
  int*   deg   = (int*)p;   p += (size_t)NN*4;
  int*   col   = (int*)p;   p += (size_t)NN*MAXDEG*4;
  float* wihT  = (float*)p; p += (size_t)3*49152*4;
  float* whhT  = (float*)p; p += (size_t)3*49152*4;
  float* WeffT = (float*)p; p += (size_t)9*49152*4;
  u16*   Bhi   = (u16*)p;   p += (size_t)9*512*256*2;
  u16*   Blo   = (u16*)p;   p += (size_t)9*512*256*2;

  k_detect<<<1, 512, 0, stream>>>(edge, batch, flags);
  hipMemsetAsync(deg, 0, (size_t)NN*4, stream);
  k_prep_wT<<<(147456 + 255)/256, 256, 0, stream>>>(gru_wih, gru_whh, wihT, whhT);
  k_weff<<<9*128, 384, 0, stream>>>(conv_w, wihT, WeffT);
  k_bsplit<<<9*512*256/256, 256, 0, stream>>>(WeffT, whhT, Bhi, Blo);
  k_fill_edges<<<NE/256, 256, 0, stream>>>(edge, flags, deg, col);
  k_enc_n<<<NN/8, 128, 0, stream>>>(x, pos, node_w1, node_b1, node_w2, node_b2, h);

  for (int l = 0; l < 3; ++l){
    for (int i = 0; i < 3; ++i){
      int li = l*3 + i;
      k_spmm<<<NN/4, 256, 0, stream>>>(deg, col, h, ah);
      k_gru_mfma<<<NN/32, 256, 0, stream>>>(ah, h, Bhi + (size_t)li*131072,
          Blo + (size_t)li*131072, gru_bih + l*384, gru_bhh + l*384, (i==2) ? 1 : 0);
    }
  }
  k_head_n<<<NN/8, 64, 0, stream>>>(h, lin1_w, lin1_b, lin2_w, lin2_b, nodeout);
  hipMemsetAsync(out, 0, (size_t)NG*16*4, stream);
  k_read<<<(NN + 15)/16, 256, 0, stream>>>(nodeout, batch, flags, out);
}

// Round 6
// 2149.536 us; speedup vs baseline: 4.6133x; 1.4745x over previous
//
#include <hip/hip_runtime.h>

#define NN 100000
#define NE 1600000
#define NG 64
#define MAXDEG 64

typedef long long i64;
typedef unsigned short u16;
typedef __attribute__((ext_vector_type(8))) _Float16 f16x8;
typedef __attribute__((ext_vector_type(4))) _Float16 half4;
typedef __attribute__((ext_vector_type(4))) float f32x4;

__device__ __forceinline__ float sigm(float x){ return 1.f/(1.f+__expf(-x)); }
__device__ __forceinline__ float tanh_(float x){ return 2.f/(1.f+__expf(-2.f*x)) - 1.f; }
__device__ __forceinline__ f32x4 mfma16h(f16x8 a, f16x8 b, f32x4 c){
  return __builtin_amdgcn_mfma_f32_16x16x32_f16(a,b,c,0,0,0);
}

// ---------------- int-width detection ----------------
__global__ __launch_bounds__(512) void k_detect(const int* __restrict__ ei,
    const int* __restrict__ batch, int* __restrict__ flags){
  int t = threadIdx.x;
  __shared__ int nz_e, nz_b;
  if (t == 0){ nz_e = 0; nz_b = 0; }
  __syncthreads();
  if (ei[2*t + 1] != 0) nz_e = 1;
  int k = NN/2 - 512 + t;
  if (batch[2*k + 1] != 0) nz_b = 1;
  __syncthreads();
  if (t == 0){ flags[0] = nz_e ? 0 : 1; flags[1] = nz_b ? 0 : 1; }
}

// ---------------- transposed GRU weights: wT[l][k][jc] = w[l][jc][k] ----------------
__global__ __launch_bounds__(256) void k_prep_wT(const float* __restrict__ wih,
    const float* __restrict__ whh, float* __restrict__ wihT, float* __restrict__ whhT){
  int idx = blockIdx.x*256 + threadIdx.x;            // 3*49152 = 147456
  if (idx >= 3*49152) return;
  int l = idx/49152, r = idx - l*49152, k = r/384, jc = r - k*384;
  wihT[idx] = wih[((size_t)l*384 + jc)*128 + k];
  whhT[idx] = whh[((size_t)l*384 + jc)*128 + k];
}

// ---------------- Weff fold: WeffT[li][k][jc] = sum_m cw[li][k][m] * wih[l][jc][m] ----------------
__global__ __launch_bounds__(384) void k_weff(const float* __restrict__ convw,
    const float* __restrict__ wihT, float* __restrict__ WeffT){
  int bid = blockIdx.x;               // 9*128
  int li = bid >> 7, k = bid & 127;
  int l = li / 3;
  int j = threadIdx.x;                // 0..383
  __shared__ float cwrow[128];
  if (j < 128) cwrow[j] = convw[((size_t)li*128 + k)*128 + j];
  __syncthreads();
  const float* wT = wihT + (size_t)l*49152;
  float acc = 0.f;
#pragma unroll 8
  for (int m = 0; m < 128; ++m)
    acc = fmaf(cwrow[m], wT[(size_t)m*384 + j], acc);
  WeffT[(size_t)li*49152 + (size_t)k*384 + j] = acc;
}

// ---------------- split fp16 B planes, MFMA-fragment-contiguous layout ----------------
// logical B[li][col(512)][k(256)]:
//   col<256: k<128 -> WeffT[li][k][col], k>=128 -> whhT[l][k-128][col]   (r,z)
//   col in [256,384): k<128 -> WeffT[li][k][col] else 0                   (inn)
//   col in [384,512): k>=128 -> whhT[l][k-128][col-128] else 0            (hn)
// storage idx (per li): (((k>>5)*512 + col)*4 + ((k>>3)&3))*8 + (k&7)
//   -> one MFMA B fragment (16 cols x 32 k) = contiguous 1 KB per wave.
__global__ __launch_bounds__(256) void k_bsplit(const float* __restrict__ WeffT,
    const float* __restrict__ whhT, u16* __restrict__ Bhi, u16* __restrict__ Blo){
  int idx = blockIdx.x*256 + threadIdx.x;   // 9*512*256 exact
  int li = idx >> 17;
  int r = idx & 131071;
  int col = r >> 8, k = r & 255;
  int l = li / 3;
  float v = 0.f;
  if (k < 128){
    if (col < 384) v = WeffT[(size_t)li*49152 + (size_t)k*384 + col];
  } else {
    int k2 = k - 128;
    if (col < 256)       v = whhT[(size_t)l*49152 + (size_t)k2*384 + col];
    else if (col >= 384) v = whhT[(size_t)l*49152 + (size_t)k2*384 + (col-128)];
  }
  _Float16 hi = (_Float16)v;
  _Float16 lo = (_Float16)(v - (float)hi);
  size_t widx = (size_t)li*131072 + ((((size_t)(k>>5))*512 + col)*4 + ((k>>3)&3))*8 + (k&7);
  Bhi[widx] = *(const u16*)&hi;
  Blo[widx] = *(const u16*)&lo;
}

// ---------------- padded adjacency by dst ----------------
__global__ __launch_bounds__(256) void k_fill_edges(const int* __restrict__ ei,
    const int* __restrict__ flags, int* __restrict__ deg, int* __restrict__ col){
  int e = blockIdx.x*256 + threadIdx.x;
  if (e >= NE) return;
  int s, d;
  if (flags[0]){
    const i64* e64 = (const i64*)ei;
    s = (int)e64[e]; d = (int)e64[NE + e];
  } else {
    s = ei[e]; d = ei[NE + e];
  }
  int slot = atomicAdd(&deg[d], 1);
  if (slot < MAXDEG) col[(size_t)d*MAXDEG + slot] = s;
}

// ---------------- encoder: fp32, 8 nodes/block (unchanged, proven) ----------------
__global__ __launch_bounds__(128) void k_enc_n(const float* __restrict__ x,
    const float* __restrict__ pos, const float* __restrict__ w1, const float* __restrict__ b1,
    const float* __restrict__ w2, const float* __restrict__ b2, float* __restrict__ h){
  int n0 = blockIdx.x * 8, j = threadIdx.x;
  __shared__ float xr[8][68];
  __shared__ float t1[8][128];
  for (int q = j; q < 8*67; q += 128){
    int p = q/67, kk = q - p*67;
    xr[p][kk] = (kk < 64) ? x[(size_t)(n0+p)*64 + kk] : pos[(size_t)(n0+p)*3 + (kk-64)];
  }
  __syncthreads();
  float s[8];
#pragma unroll
  for (int p=0;p<8;++p) s[p] = b1[j];
  for (int k=0;k<67;++k){
    float w = w1[k*128 + j];
#pragma unroll
    for (int p=0;p<8;++p) s[p] = fmaf(xr[p][k], w, s[p]);
  }
#pragma unroll
  for (int p=0;p<8;++p) t1[p][j] = fmaxf(s[p], 0.f);
  __syncthreads();
#pragma unroll
  for (int p=0;p<8;++p) s[p] = b2[j];
  for (int k=0;k<128;++k){
    float w = w2[k*128 + j];
#pragma unroll
    for (int p=0;p<8;++p) s[p] = fmaf(t1[p][k], w, s[p]);
  }
#pragma unroll
  for (int p=0;p<8;++p) h[(size_t)(n0+p)*128 + j] = s[p];
}

// ---------------- SpMM gather (unchanged) ----------------
__global__ __launch_bounds__(256) void k_spmm(const int* __restrict__ deg,
    const int* __restrict__ col, const float* __restrict__ h, float* __restrict__ ah){
  int node = (blockIdx.x<<2) + (threadIdx.x>>6);
  int lane = threadIdx.x & 63;
  int d = deg[node]; d = min(d, MAXDEG);
  int mysrc = col[(size_t)node*MAXDEG + lane];
  float ax = 0.f, ay = 0.f;
  for (int s = 0; s < d; ++s){
    int src = __shfl(mysrc, s, 64);
    float2 v = *(const float2*)(h + (size_t)src*128 + (lane<<1));
    ax += v.x; ay += v.y;
  }
  float2 o; o.x = ax; o.y = ay;
  *(float2*)(ah + (size_t)node*128 + (lane<<1)) = o;
}

// ---------------- fused GRU: split-fp16 3-pass MFMA, 64-row tile, 8 waves ----------------
// A = [ah | h] per node (K=256), hi/lo fp16 in LDS (XOR-swizzled chunks).
// groups: 0=r(cols0-127), 1=z, 2=inn(K<128), 3=hn(K>=128). wave w owns cols w*16..+15 of each group.
__global__ __launch_bounds__(512, 4) void k_gru_mfma(const float* __restrict__ ah,
    float* __restrict__ h, const u16* __restrict__ Bhi, const u16* __restrict__ Blo,
    const float* __restrict__ bih, const float* __restrict__ bhh, int apply_relu){
  __shared__ u16 Ahi[64*256];
  __shared__ u16 Alo[64*256];
  const int tid = threadIdx.x, lane = tid & 63, w = tid >> 6;   // w in 0..7
  const int tile = blockIdx.x * 64;

  // stage: ah -> cols 0..127, h -> cols 128..255, split hi/lo, swizzled
#pragma unroll
  for (int half = 0; half < 2; ++half){
    const float* src = half ? h : ah;
#pragma unroll
    for (int i = 0; i < 4; ++i){
      int f = i*512 + tid;                   // 0..2047
      int row = f >> 5, colq = f & 31;
      int n = tile + row;
      float4 v = {0.f,0.f,0.f,0.f};
      if (n < NN) v = *(const float4*)(src + (size_t)n*128 + colq*4);
      int colu = half*128 + colq*4;
      int chunk = colu >> 3, e4 = colu & 7;  // e4 in {0,4}
      int cs = chunk ^ (row & 7);
      int idx = row*256 + cs*8 + e4;
      _Float16 h0=(_Float16)v.x, h1=(_Float16)v.y, h2=(_Float16)v.z, h3=(_Float16)v.w;
      _Float16 l0=(_Float16)(v.x-(float)h0), l1=(_Float16)(v.y-(float)h1),
               l2=(_Float16)(v.z-(float)h2), l3=(_Float16)(v.w-(float)h3);
      half4 hv = {h0,h1,h2,h3};
      half4 lv = {l0,l1,l2,l3};
      *(half4*)(Ahi + idx) = hv;
      *(half4*)(Alo + idx) = lv;
    }
  }
  __syncthreads();

  const f32x4 fz = {0.f,0.f,0.f,0.f};
  f32x4 acc[4][4];
#pragma unroll
  for (int g=0;g<4;++g)
#pragma unroll
    for (int R=0;R<4;++R) acc[g][R] = fz;

#pragma unroll
  for (int kk = 0; kk < 8; ++kk){
    f16x8 a_hi[4], a_lo[4];
#pragma unroll
    for (int R=0;R<4;++R){
      int arow = R*16 + (lane&15);
      int cs = (kk*4 + (lane>>4)) ^ (arow & 7);
      a_hi[R] = *(const f16x8*)(Ahi + arow*256 + cs*8);
      a_lo[R] = *(const f16x8*)(Alo + arow*256 + cs*8);
    }
#pragma unroll
    for (int g=0; g<4; ++g){
      if (g==2 && kk>=4) continue;   // inn: K[0,128) only
      if (g==3 && kk<4) continue;    // hn : K[128,256) only
      int colg = g*128 + w*16 + (lane&15);
      size_t boff = (((size_t)kk*512 + colg)*4 + (lane>>4))*8;
      f16x8 bh = *(const f16x8*)(Bhi + boff);
      f16x8 bl = *(const f16x8*)(Blo + boff);
#pragma unroll
      for (int R=0;R<4;++R){
        acc[g][R] = mfma16h(a_hi[R], bh, acc[g][R]);
        acc[g][R] = mfma16h(a_hi[R], bl, acc[g][R]);
        acc[g][R] = mfma16h(a_lo[R], bh, acc[g][R]);
      }
    }
  }

  {
    int jj = w*16 + (lane&15);
    float br  = bih[jj]     + bhh[jj];
    float bz  = bih[128+jj] + bhh[128+jj];
    float bin = bih[256+jj];
    float bhn = bhh[256+jj];
#pragma unroll
    for (int R=0;R<4;++R)
#pragma unroll
      for (int v=0;v<4;++v){
        int r_ = R*16 + ((lane>>4)<<2) + v;
        int n = tile + r_;
        float rg = sigm(acc[0][R][v] + br);
        float zg = sigm(acc[1][R][v] + bz);
        float hnv = acc[3][R][v] + bhn;
        float ng = tanh_(acc[2][R][v] + bin + rg*hnv);
        int colu = 128 + jj;
        int cs = (colu >> 3) ^ (r_ & 7);
        int lidx = r_*256 + cs*8 + (colu & 7);
        float hold = (float)(*(const _Float16*)(Ahi + lidx))
                   + (float)(*(const _Float16*)(Alo + lidx));
        float hnew = (1.f - zg)*ng + zg*hold;
        if (apply_relu) hnew = fmaxf(hnew, 0.f);
        if (n < NN) h[(size_t)n*128 + jj] = hnew;
      }
  }
}

// ---------------- head: fp32, 8 nodes/block (unchanged) ----------------
__global__ __launch_bounds__(64) void k_head_n(const float* __restrict__ h,
    const float* __restrict__ l1, const float* __restrict__ b1,
    const float* __restrict__ l2, const float* __restrict__ b2, float* __restrict__ nodeout){
  int n0 = blockIdx.x * 8, j = threadIdx.x;
  __shared__ float hrow[8][128], t[8][64];
  for (int q = j; q < 1024; q += 64){
    int p = q >> 7, k = q & 127;
    hrow[p][k] = h[(size_t)(n0+p)*128 + k];
  }
  __syncthreads();
  float s[8];
#pragma unroll
  for (int p=0;p<8;++p) s[p] = b1[j];
  for (int k=0;k<128;++k){
    float w = l1[k*64 + j];
#pragma unroll
    for (int p=0;p<8;++p) s[p] = fmaf(hrow[p][k], w, s[p]);
  }
#pragma unroll
  for (int p=0;p<8;++p) t[p][j] = fmaxf(s[p], 0.f);
  __syncthreads();
  int c = j & 15;
#pragma unroll
  for (int pp=0;pp<2;++pp){
    int p = (j >> 4) + pp*4;
    float o = b2[c];
    for (int k=0;k<64;++k) o = fmaf(t[p][k], l2[k*16 + c], o);
    nodeout[(size_t)(n0+p)*16 + c] = o;
  }
}

// ---------------- per-graph readout: segmented reduce (batch is sorted) ----------------
__device__ __forceinline__ int lbound32(const int* __restrict__ a, int n, int v){
  int lo = 0, hi = n;
  while (lo < hi){ int mid = (lo+hi)>>1; if (a[mid] < v) lo = mid+1; else hi = mid; }
  return lo;
}
__device__ __forceinline__ int lbound64(const i64* __restrict__ a, int n, i64 v){
  int lo = 0, hi = n;
  while (lo < hi){ int mid = (lo+hi)>>1; if (a[mid] < v) lo = mid+1; else hi = mid; }
  return lo;
}
__global__ __launch_bounds__(256) void k_reduce(const float* __restrict__ nodeout,
    const int* __restrict__ batch, const int* __restrict__ flags, float* __restrict__ out){
  int g = blockIdx.x;
  int lo, hi;
  if (flags[1]){
    const i64* b64 = (const i64*)batch;
    lo = lbound64(b64, NN, (i64)g); hi = lbound64(b64, NN, (i64)g+1);
  } else {
    lo = lbound32(batch, NN, g); hi = lbound32(batch, NN, g+1);
  }
  int tid = threadIdx.x;
  int c = tid & 15, rr = tid >> 4;
  float s = 0.f;
  for (int r = lo + rr; r < hi; r += 16) s += nodeout[(size_t)r*16 + c];
  __shared__ float red[256];
  red[tid] = s; __syncthreads();
  for (int step = 128; step >= 16; step >>= 1){
    if (tid < step) red[tid] += red[tid + step];
    __syncthreads();
  }
  if (tid < 16) out[g*16 + tid] = red[tid];
}

// ---------------- launch ----------------
extern "C" void kernel_launch(void* const* d_in, const int* in_sizes, int n_in,
                              void* d_out, int out_size, void* d_ws, size_t ws_size,
                              hipStream_t stream){
  const float* x        = (const float*)d_in[0];
  const float* pos      = (const float*)d_in[1];
  const int*   edge     = (const int*)d_in[2];
  const int*   batch    = (const int*)d_in[3];
  const float* node_w1  = (const float*)d_in[4];
  const float* node_b1  = (const float*)d_in[5];
  const float* node_w2  = (const float*)d_in[6];
  const float* node_b2  = (const float*)d_in[7];
  const float* conv_w   = (const float*)d_in[8];
  const float* gru_wih  = (const float*)d_in[9];
  const float* gru_whh  = (const float*)d_in[10];
  const float* gru_bih  = (const float*)d_in[11];
  const float* gru_bhh  = (const float*)d_in[12];
  const float* lin1_w   = (const float*)d_in[13];
  const float* lin1_b   = (const float*)d_in[14];
  const float* lin2_w   = (const float*)d_in[15];
  const float* lin2_b   = (const float*)d_in[16];
  float* out = (float*)d_out;

  char* p = (char*)d_ws;
  int*   flags = (int*)p;   p += 256;
  float* h     = (float*)p; p += (size_t)NN*128*4;
  float* ah    = (float*)p; p += (size_t)NN*128*4;
  float* nodeout = (float*)p; p += (size_t)NN*16*4;
  int*   deg   = (int*)p;   p += (size_t)NN*4;
  int*   col   = (int*)p;   p += (size_t)NN*MAXDEG*4;
  float* wihT  = (float*)p; p += (size_t)3*49152*4;
  float* whhT  = (float*)p; p += (size_t)3*49152*4;
  float* WeffT = (float*)p; p += (size_t)9*49152*4;
  u16*   Bhi   = (u16*)p;   p += (size_t)9*512*256*2;
  u16*   Blo   = (u16*)p;   p += (size_t)9*512*256*2;

  k_detect<<<1, 512, 0, stream>>>(edge, batch, flags);
  hipMemsetAsync(deg, 0, (size_t)NN*4, stream);
  k_prep_wT<<<(147456 + 255)/256, 256, 0, stream>>>(gru_wih, gru_whh, wihT, whhT);
  k_weff<<<9*128, 384, 0, stream>>>(conv_w, wihT, WeffT);
  k_bsplit<<<9*512*256/256, 256, 0, stream>>>(WeffT, whhT, Bhi, Blo);
  k_fill_edges<<<NE/256, 256, 0, stream>>>(edge, flags, deg, col);
  k_enc_n<<<NN/8, 128, 0, stream>>>(x, pos, node_w1, node_b1, node_w2, node_b2, h);

  for (int l = 0; l < 3; ++l){
    for (int i = 0; i < 3; ++i){
      int li = l*3 + i;
      k_spmm<<<NN/4, 256, 0, stream>>>(deg, col, h, ah);
      k_gru_mfma<<<(NN + 63)/64, 512, 0, stream>>>(ah, h, Bhi + (size_t)li*131072,
          Blo + (size_t)li*131072, gru_bih + l*384, gru_bhh + l*384, (i==2) ? 1 : 0);
    }
  }
  k_head_n<<<NN/8, 64, 0, stream>>>(h, lin1_w, lin1_b, lin2_w, lin2_b, nodeout);
  k_reduce<<<NG, 256, 0, stream>>>(nodeout, batch, flags, out);
}